// Round 4
// baseline (377.900 us; speedup 1.0000x reference)
//
#include <hip/hip_runtime.h>

// ============================================================================
// MHAtt with geometric box positional bias — MI355X/gfx950.
// B=32 N=256 DM=512 H=8 DH=64.
// DTYPES (validated round 3): inputs float32, mask int32, OUTPUTS float32
// (reference output dtype). Internal ws tensors bf16 (MFMA operands).
//
// Pipeline (7 dispatches):
//   K0 transpose_kernel : Wq/Wk/Wv/Wm f32 [512,512] -> bf16 WT[n][k] in ws
//   K1 pos_kernel       : ps[b,i,j] = relu(geo sin/cos @ Wbox + bbox) -> d_out
//                         pos region (f32), tiled across 8 heads
//   K2 gemm<f32,0/0/1>  : qh=[B,H,N,DH], kh=[B,H,N,DH], vT=[B,H,DH,N] (bf16 ws)
//   K3 attn_kernel      : S=QK^T*scale + pos + mask, register softmax,
//                         P->LDS->A-frags, P@V -> attw [B*N, DM] (bf16 ws)
//   K4 gemm<bf16,2>     : attw @ Wm + bm -> d_out atted region (f32)
//
// MFMA 16x16x32 bf16 layouts (verified m89/m91; cross-checked vs scalar
// oracle in round 3 — identical absmax):
//   A: lane holds A[m=lane&15][k=(lane>>4)*8+j]   (16B contiguous)
//   B: lane holds B[k=(lane>>4)*8+j][n=lane&15]   (contiguous if B stored n-major)
//   C/D: col=lane&15, row=(lane>>4)*4+reg
// ============================================================================

typedef __bf16 bf16_t;
typedef __bf16 bf16x8 __attribute__((ext_vector_type(8)));
typedef float  f32x4  __attribute__((ext_vector_type(4)));
typedef float  f32x8  __attribute__((ext_vector_type(8)));

#define NB    32
#define NSEQ  256
#define DMODEL 512
#define NH    8
#define DHEAD 64
#define M_ROWS (NB * NSEQ)              // 8192
#define ATTED_ELEMS (M_ROWS * DMODEL)   // 4,194,304 f32

// ws layout (bf16 elements); total 17,825,792 elems = 35.7 MB
#define WS_WT    0          // 4 * 512*512
#define WS_QH    1048576    // [B,H,N,DH]
#define WS_KH    5242880    // [B,H,N,DH]
#define WS_VT    9437184    // [B,H,DH,N]
#define WS_ATTW  13631488   // [B*N, DM]

// A-fragment loaders: 8 contiguous K-elements -> bf16x8
__device__ inline bf16x8 load_frag(const bf16_t* p) { return *(const bf16x8*)p; }
__device__ inline bf16x8 load_frag(const float* p) {
  f32x8 v = *(const f32x8*)p;
  bf16x8 r;
#pragma unroll
  for (int j = 0; j < 8; j++) r[j] = (bf16_t)v[j];
  return r;
}

// ---------------------------------------------------------------------------
// Wq/Wk/Wv/Wm (f32, [k][n]) -> WT (bf16, [n][k])
__global__ __launch_bounds__(256) void transpose_kernel(
    const float* __restrict__ W0, const float* __restrict__ W1,
    const float* __restrict__ W2, const float* __restrict__ W3,
    bf16_t* __restrict__ wt) {
  int m = blockIdx.y;
  const float* W = (m == 0) ? W0 : (m == 1) ? W1 : (m == 2) ? W2 : W3;
  bf16_t* WT = wt + m * (DMODEL * DMODEL);
  int o = blockIdx.x * 256 + threadIdx.x;   // 0..262143
  int n = o >> 9, k = o & 511;
  WT[o] = (bf16_t)W[k * DMODEL + n];
}

// ---------------------------------------------------------------------------
// ps[b,i,j]; one block per (b,i), thread j. Writes all 8 head copies (f32).
__global__ __launch_bounds__(256) void pos_kernel(
    const float* __restrict__ box, const float* __restrict__ Wbox,
    const float* __restrict__ bbox, float* __restrict__ pos_out) {
  __shared__ float wb[64];
  __shared__ float bb;
  int tid = threadIdx.x;
  if (tid < 64) wb[tid] = Wbox[tid];
  if (tid == 0) bb = bbox[0];
  __syncthreads();

  int bx = blockIdx.x;
  int b = bx >> 8, i = bx & 255, j = tid;

  float4 bi = *(const float4*)(box + (size_t)(b * NSEQ + i) * 4);
  float4 bj = *(const float4*)(box + (size_t)(b * NSEQ + j) * 4);

  float cxi = (bi.x + bi.z) * 0.5f, cyi = (bi.y + bi.w) * 0.5f;
  float wi = bi.z - bi.x + 1.0f,    hi = bi.w - bi.y + 1.0f;
  float cxj = (bj.x + bj.z) * 0.5f, cyj = (bj.y + bj.w) * 0.5f;
  float wj = bj.z - bj.x + 1.0f,    hj = bj.w - bj.y + 1.0f;

  float dx = __logf(fmaxf(fabsf((cxi - cxj) / wi), 1e-3f));
  float dy = __logf(fmaxf(fabsf((cyi - cyj) / hi), 1e-3f));
  float dw = __logf(wi / wj);
  float dh = __logf(hi / hj);

  // dim_mat[f] = 1000^(-f/8)
  const float dim_mat[8] = {1.0f, 0.42169650342f, 0.177827941f, 0.074989421f,
                            0.0316227766f, 0.0133352143f, 0.00562341325f, 0.00237137371f};
  float p4[4] = {dx, dy, dw, dh};
  float acc = bb;
#pragma unroll
  for (int c = 0; c < 4; c++) {
    float base = 100.0f * p4[c];
#pragma unroll
    for (int f = 0; f < 8; f++) {
      float sn, cs;
      __sincosf(base * dim_mat[f], &sn, &cs);
      acc += sn * wb[c * 8 + f] + cs * wb[32 + c * 8 + f];
    }
  }
  float pv = fmaxf(acc, 0.0f);
  size_t base_bi = ((size_t)b * NH * NSEQ + i) * NSEQ + j;  // h=0 slot
#pragma unroll
  for (int h = 0; h < NH; h++)
    pos_out[base_bi + (size_t)h * NSEQ * NSEQ] = pv;
}

// ---------------------------------------------------------------------------
// C[M=8192,512] = A[8192,512] @ W + bias; W given transposed (bf16 WT[n][k]).
// Block = 4 waves, 64 rows x 128 cols; wave = 16 rows x 8 n-tiles.
// MODE 0: out[((b*8+h)*256+n)*64+d]   bf16 (q,k headed layout)
// MODE 1: out[((b*8+h)*64+d)*256+n]   bf16 (v transposed-headed layout)
// MODE 2: out[gm*512+gc]              f32  (plain row-major, final atted)
template <typename AT, int MODE, typename OT>
__global__ __launch_bounds__(256) void gemm_kernel(
    const AT* __restrict__ A, const bf16_t* __restrict__ WT,
    const float* __restrict__ bias, OT* __restrict__ out) {
  int tid = threadIdx.x;
  int wave = tid >> 6, lane = tid & 63, quad = lane >> 4, l16 = lane & 15;
  int bm = blockIdx.x, bn = blockIdx.y;

  const AT* arow = A + (size_t)(bm * 64 + wave * 16 + l16) * DMODEL;
  int kbase = quad * 8;

  f32x4 acc[8];
#pragma unroll
  for (int t = 0; t < 8; t++) acc[t] = (f32x4){0.f, 0.f, 0.f, 0.f};

  for (int kk = 0; kk < 16; kk++) {
    int k0 = kk * 32 + kbase;
    bf16x8 a = load_frag(arow + k0);
#pragma unroll
    for (int t = 0; t < 8; t++) {
      int n = bn * 128 + t * 16 + l16;
      bf16x8 bfr = *(const bf16x8*)(WT + (size_t)n * DMODEL + k0);
      acc[t] = __builtin_amdgcn_mfma_f32_16x16x32_bf16(a, bfr, acc[t], 0, 0, 0);
    }
  }

#pragma unroll
  for (int t = 0; t < 8; t++) {
    int gc = bn * 128 + t * 16 + l16;
    float bs = bias[gc];
#pragma unroll
    for (int r = 0; r < 4; r++) {
      int gm = bm * 64 + wave * 16 + quad * 4 + r;
      float val = acc[t][r] + bs;
      size_t idx;
      if (MODE == 0) {
        int b = gm >> 8, n = gm & 255, h = gc >> 6, d = gc & 63;
        idx = ((size_t)(b * NH + h) * NSEQ + n) * DHEAD + d;
      } else if (MODE == 1) {
        int b = gm >> 8, n = gm & 255, h = gc >> 6, d = gc & 63;
        idx = ((size_t)(b * NH + h) * DHEAD + d) * NSEQ + n;
      } else {
        idx = (size_t)gm * DMODEL + gc;
      }
      out[idx] = (OT)val;
    }
  }
}

// ---------------------------------------------------------------------------
// Attention: block = (b, h, 64-query tile), 4 waves x 16 rows each.
// P_s rows padded to 264 bf16 (528 B = 33x16B, 16B-aligned, bank-spread).
__global__ __launch_bounds__(256) void attn_kernel(
    const bf16_t* __restrict__ qh, const bf16_t* __restrict__ kh,
    const bf16_t* __restrict__ vT, const float* __restrict__ pos,
    const int* __restrict__ mask, bf16_t* __restrict__ attw) {
  __shared__ bf16_t P_s[64 * 264];

  int tid = threadIdx.x;
  int wave = tid >> 6, lane = tid & 63, quad = lane >> 4, l16 = lane & 15;
  int qt = blockIdx.x, h = blockIdx.y, b = blockIdx.z;

  const bf16_t* qb = qh + (size_t)(b * NH + h) * NSEQ * DHEAD;
  const bf16_t* kb = kh + (size_t)(b * NH + h) * NSEQ * DHEAD;
  const bf16_t* vb = vT + (size_t)(b * NH + h) * DHEAD * NSEQ;
  // heads share identical pos values; read the h=0 copy for L2 locality
  const float* pb = pos + (size_t)b * NH * NSEQ * NSEQ;
  const int* mrow = mask + b * NSEQ;

  int m0 = qt * 64 + wave * 16;

  // Phase A: S = qh @ kh^T  (16 key-tiles of 16, K=64 as two 32-chunks)
  bf16x8 a0 = *(const bf16x8*)(qb + (size_t)(m0 + l16) * DHEAD + quad * 8);
  bf16x8 a1 = *(const bf16x8*)(qb + (size_t)(m0 + l16) * DHEAD + 32 + quad * 8);
  f32x4 s[16];
#pragma unroll
  for (int t = 0; t < 16; t++) s[t] = (f32x4){0.f, 0.f, 0.f, 0.f};
#pragma unroll
  for (int t = 0; t < 16; t++) {
    const bf16_t* krow = kb + (size_t)(t * 16 + l16) * DHEAD;
    bf16x8 b0 = *(const bf16x8*)(krow + quad * 8);
    bf16x8 b1 = *(const bf16x8*)(krow + 32 + quad * 8);
    s[t] = __builtin_amdgcn_mfma_f32_16x16x32_bf16(a0, b0, s[t], 0, 0, 0);
    s[t] = __builtin_amdgcn_mfma_f32_16x16x32_bf16(a1, b1, s[t], 0, 0, 0);
  }

  // Phase B: scale + pos + mask (C-layout: row=quad*4+r, col=t*16+l16)
#pragma unroll
  for (int t = 0; t < 16; t++) {
    int gj = t * 16 + l16;
    int mk = mrow[gj];
#pragma unroll
    for (int r = 0; r < 4; r++) {
      int gr = m0 + quad * 4 + r;
      float v = s[t][r] * 0.125f + pb[(size_t)gr * NSEQ + gj];
      s[t][r] = mk ? -1e9f : v;
    }
  }

  // Register softmax: each row lives across the 16 lanes of a quad.
  float inv[4];
#pragma unroll
  for (int r = 0; r < 4; r++) {
    float m = -1e30f;
#pragma unroll
    for (int t = 0; t < 16; t++) m = fmaxf(m, s[t][r]);
    m = fmaxf(m, __shfl_xor(m, 1));
    m = fmaxf(m, __shfl_xor(m, 2));
    m = fmaxf(m, __shfl_xor(m, 4));
    m = fmaxf(m, __shfl_xor(m, 8));
    float sum = 0.f;
#pragma unroll
    for (int t = 0; t < 16; t++) {
      float e = __expf(s[t][r] - m);
      s[t][r] = e;
      sum += e;
    }
    sum += __shfl_xor(sum, 1);
    sum += __shfl_xor(sum, 2);
    sum += __shfl_xor(sum, 4);
    sum += __shfl_xor(sum, 8);
    inv[r] = 1.0f / sum;
  }

  // P (bf16) -> LDS in row-major A-readable layout.
#pragma unroll
  for (int t = 0; t < 16; t++) {
    int gj = t * 16 + l16;
#pragma unroll
    for (int r = 0; r < 4; r++)
      P_s[(wave * 16 + quad * 4 + r) * 264 + gj] = (bf16_t)(s[t][r] * inv[r]);
  }
  __syncthreads();

  // Phase C: O = P @ V  (V pre-transposed [DH][N] -> contiguous B-frags)
  f32x4 o[4];
#pragma unroll
  for (int t2 = 0; t2 < 4; t2++) o[t2] = (f32x4){0.f, 0.f, 0.f, 0.f};
#pragma unroll
  for (int kk = 0; kk < 8; kk++) {
    bf16x8 pa = *(const bf16x8*)(&P_s[(wave * 16 + l16) * 264 + kk * 32 + quad * 8]);
#pragma unroll
    for (int t2 = 0; t2 < 4; t2++) {
      bf16x8 vv = *(const bf16x8*)(vb + (size_t)(t2 * 16 + l16) * NSEQ + kk * 32 + quad * 8);
      o[t2] = __builtin_amdgcn_mfma_f32_16x16x32_bf16(pa, vv, o[t2], 0, 0, 0);
    }
  }

  // Epilogue: attw[(b*256+q)*512 + h*64+d]
#pragma unroll
  for (int t2 = 0; t2 < 4; t2++) {
    int d = t2 * 16 + l16;
#pragma unroll
    for (int r = 0; r < 4; r++) {
      int gr = m0 + quad * 4 + r;
      attw[(size_t)(b * NSEQ + gr) * DMODEL + h * DHEAD + d] = (bf16_t)o[t2][r];
    }
  }
}

// ---------------------------------------------------------------------------
extern "C" void kernel_launch(void* const* d_in, const int* in_sizes, int n_in,
                              void* d_out, int out_size, void* d_ws, size_t ws_size,
                              hipStream_t stream) {
  const float* v    = (const float*)d_in[0];
  const float* k    = (const float*)d_in[1];
  const float* q    = (const float*)d_in[2];
  const float* box  = (const float*)d_in[3];
  const int*   mask = (const int*)d_in[4];
  // d_in[5] = fg (always 2; branch fixed)
  const float* Wq   = (const float*)d_in[6];
  const float* bq   = (const float*)d_in[7];
  const float* Wk   = (const float*)d_in[8];
  const float* bk   = (const float*)d_in[9];
  const float* Wv   = (const float*)d_in[10];
  const float* bv   = (const float*)d_in[11];
  const float* Wm   = (const float*)d_in[12];
  const float* bm   = (const float*)d_in[13];
  const float* Wbox = (const float*)d_in[14];
  const float* bbox = (const float*)d_in[15];

  float* out  = (float*)d_out;
  bf16_t* ws  = (bf16_t*)d_ws;
  bf16_t* WT   = ws + WS_WT;
  bf16_t* qh   = ws + WS_QH;
  bf16_t* khw  = ws + WS_KH;
  bf16_t* vT   = ws + WS_VT;
  bf16_t* attw = ws + WS_ATTW;
  float* pos  = out + ATTED_ELEMS;   // pos_scores region of d_out (f32)

  transpose_kernel<<<dim3(1024, 4), dim3(256), 0, stream>>>(Wq, Wk, Wv, Wm, WT);
  pos_kernel<<<dim3(NB * NSEQ), dim3(256), 0, stream>>>(box, Wbox, bbox, pos);
  gemm_kernel<float, 0, bf16_t><<<dim3(128, 4), dim3(256), 0, stream>>>(q, WT + 0 * 262144, bq, qh);
  gemm_kernel<float, 0, bf16_t><<<dim3(128, 4), dim3(256), 0, stream>>>(k, WT + 1 * 262144, bk, khw);
  gemm_kernel<float, 1, bf16_t><<<dim3(128, 4), dim3(256), 0, stream>>>(v, WT + 2 * 262144, bv, vT);
  attn_kernel<<<dim3(NSEQ / 64, NH, NB), dim3(256), 0, stream>>>(qh, khw, vT, pos, mask, attw);
  gemm_kernel<bf16_t, 2, float><<<dim3(128, 4), dim3(256), 0, stream>>>(attw, WT + 3 * 262144, bm, out);
}

// Round 5
// 248.702 us; speedup vs baseline: 1.5195x; 1.5195x over previous
//
#include <hip/hip_runtime.h>

// ============================================================================
// MHAtt with geometric box positional bias — MI355X/gfx950. Round 5.
// B=32 N=256 DM=512 H=8 DH=64. Inputs f32, mask int32, outputs f32.
// Internal ws tensors bf16.
//
// Round-4 profile: projection GEMMs 52 µs each, MfmaUtil 2.8%, occupancy 19%
// -> latency-bound scattered gathers. Fix: m93/m97-style LDS-staged GEMM
// (128x128 tile, BK=32, f32->bf16 cvt fused into A staging), QKV fused into
// one dispatch (grid z=3); attn stages K in LDS (aliased by P after use).
//
// 5 dispatches:
//   K0 transpose_kernel : W* f32 [k][n] -> bf16 WT[n][k], LDS-tiled
//   K1 pos_kernel       : relu(geo sin/cos @ Wbox + bbox) -> d_out pos (f32 x8)
//   K2 gemm128<float>   : fused q/k/v projections (z=0,1,2) -> qh, kh, vT (bf16)
//   K3 attn_kernel      : S=QK^T*scale+pos+mask, reg softmax, P@V -> attw
//   K4 gemm128<bf16>    : attw @ Wm + bm -> d_out atted (f32), mode 2
//
// MFMA 16x16x32 bf16 layouts (verified m89/m91 + round-3 scalar oracle):
//   A: lane holds A[m=lane&15][k=(lane>>4)*8+j]   (16B contiguous)
//   B: lane holds B[k=(lane>>4)*8+j][n=lane&15]   (contiguous, B stored n-major)
//   C/D: col=lane&15, row=(lane>>4)*4+reg
// ============================================================================

typedef __bf16 bf16_t;
typedef __bf16 bf16x8 __attribute__((ext_vector_type(8)));
typedef float  f32x4  __attribute__((ext_vector_type(4)));
typedef float  f32x8  __attribute__((ext_vector_type(8)));

#define NB    32
#define NSEQ  256
#define DMODEL 512
#define NH    8
#define DHEAD 64
#define M_ROWS (NB * NSEQ)              // 8192
#define ATTED_ELEMS (M_ROWS * DMODEL)   // 4,194,304 f32
#define HEAD_T_ELEMS 4194304            // elems of one [B,H,N,DH]-class tensor

// ws layout (bf16 elements); total 17,825,792 elems = 35.7 MB (round-4 safe)
#define WS_WT    0          // 4 * 512*512
#define WS_QH    1048576    // [B,H,N,DH]   (q: +0, k: +4.19M, vT: +8.39M)
#define WS_ATTW  13631488   // [B*N, DM]

// 8 contiguous K-elements -> bf16x8 (with f32 conversion when needed)
__device__ inline bf16x8 load8(const bf16_t* p) { return *(const bf16x8*)p; }
__device__ inline bf16x8 load8(const float* p) {
  f32x8 v = *(const f32x8*)p;
  bf16x8 r;
#pragma unroll
  for (int j = 0; j < 8; j++) r[j] = (bf16_t)v[j];
  return r;
}

// ---------------------------------------------------------------------------
// W (f32, [k][n]) -> WT (bf16, [n][k]), 64x64 LDS tiles, both sides coalesced.
__global__ __launch_bounds__(256) void transpose_kernel(
    const float* __restrict__ W0, const float* __restrict__ W1,
    const float* __restrict__ W2, const float* __restrict__ W3,
    bf16_t* __restrict__ wt) {
  __shared__ float T_s[64 * 65];
  int tid = threadIdx.x;
  int m = blockIdx.z;
  const float* W = (m == 0) ? W0 : (m == 1) ? W1 : (m == 2) ? W2 : W3;
  bf16_t* WT = wt + m * (DMODEL * DMODEL);
  int k0 = blockIdx.x * 64, n0 = blockIdx.y * 64;
#pragma unroll
  for (int i = 0; i < 16; i++) {
    int idx = tid + i * 256;
    int r = idx >> 6, c = idx & 63;
    T_s[r * 65 + c] = W[(size_t)(k0 + r) * DMODEL + n0 + c];   // coalesced read
  }
  __syncthreads();
#pragma unroll
  for (int i = 0; i < 16; i++) {
    int idx = tid + i * 256;
    int r = idx >> 6, c = idx & 63;
    WT[(size_t)(n0 + r) * DMODEL + k0 + c] = (bf16_t)T_s[c * 65 + r];  // coalesced write
  }
}

// ---------------------------------------------------------------------------
// ps[b,i,j]; one block per (b,i), thread j. Writes all 8 head copies (f32).
__global__ __launch_bounds__(256) void pos_kernel(
    const float* __restrict__ box, const float* __restrict__ Wbox,
    const float* __restrict__ bbox, float* __restrict__ pos_out) {
  __shared__ float wb[64];
  __shared__ float bb;
  int tid = threadIdx.x;
  if (tid < 64) wb[tid] = Wbox[tid];
  if (tid == 0) bb = bbox[0];
  __syncthreads();

  int bx = blockIdx.x;
  int b = bx >> 8, i = bx & 255, j = tid;

  float4 bi = *(const float4*)(box + (size_t)(b * NSEQ + i) * 4);
  float4 bj = *(const float4*)(box + (size_t)(b * NSEQ + j) * 4);

  float cxi = (bi.x + bi.z) * 0.5f, cyi = (bi.y + bi.w) * 0.5f;
  float wi = bi.z - bi.x + 1.0f,    hi = bi.w - bi.y + 1.0f;
  float cxj = (bj.x + bj.z) * 0.5f, cyj = (bj.y + bj.w) * 0.5f;
  float wj = bj.z - bj.x + 1.0f,    hj = bj.w - bj.y + 1.0f;

  float dx = __logf(fmaxf(fabsf((cxi - cxj) / wi), 1e-3f));
  float dy = __logf(fmaxf(fabsf((cyi - cyj) / hi), 1e-3f));
  float dw = __logf(wi / wj);
  float dh = __logf(hi / hj);

  // dim_mat[f] = 1000^(-f/8)
  const float dim_mat[8] = {1.0f, 0.42169650342f, 0.177827941f, 0.074989421f,
                            0.0316227766f, 0.0133352143f, 0.00562341325f, 0.00237137371f};
  float p4[4] = {dx, dy, dw, dh};
  float acc = bb;
#pragma unroll
  for (int c = 0; c < 4; c++) {
    float base = 100.0f * p4[c];
#pragma unroll
    for (int f = 0; f < 8; f++) {
      float sn, cs;
      __sincosf(base * dim_mat[f], &sn, &cs);
      acc += sn * wb[c * 8 + f] + cs * wb[32 + c * 8 + f];
    }
  }
  float pv = fmaxf(acc, 0.0f);
  size_t base_bi = ((size_t)b * NH * NSEQ + i) * NSEQ + j;  // h=0 slot
#pragma unroll
  for (int h = 0; h < NH; h++)
    pos_out[base_bi + (size_t)h * NSEQ * NSEQ] = pv;
}

// ---------------------------------------------------------------------------
// LDS-staged GEMM, 128x128 block tile, BK=32, 4 waves (2x2 of 64x64).
// C[8192,512] = A @ W + bias, W pre-transposed bf16 (WT[n][k]).
// final_mode==0: fused QKV (z=blockIdx.z selects A/bias/out-tensor; z==2 -> vT)
// final_mode==2: final projection (A=attw bf16, out f32 row-major)
// A_s/B_s rows padded to 40 bf16 (80 B) — m97-class bank pattern.
template <typename AT>
__global__ __launch_bounds__(256) void gemm128_kernel(
    const AT* __restrict__ A0, const AT* __restrict__ A1, const AT* __restrict__ A2,
    const bf16_t* __restrict__ WTbase,
    const float* __restrict__ bias0, const float* __restrict__ bias1,
    const float* __restrict__ bias2,
    bf16_t* __restrict__ outb,   // ws qh base (q/k/vT contiguous) for modes 0/1
    float* __restrict__ outf,    // f32 d_out for mode 2
    int final_mode) {
  __shared__ bf16_t A_s[128 * 40];
  __shared__ bf16_t B_s[128 * 40];

  int tid = threadIdx.x;
  int wave = tid >> 6, lane = tid & 63, quad = lane >> 4, l16 = lane & 15;
  int wm = wave >> 1, wn = wave & 1;
  int bm = blockIdx.x, bn = blockIdx.y, z = blockIdx.z;

  const AT* A = (z == 0) ? A0 : (z == 1) ? A1 : A2;
  const float* bias = (z == 0) ? bias0 : (z == 1) ? bias1 : bias2;
  const bf16_t* WT = WTbase + (size_t)(final_mode == 2 ? 3 : z) * 262144;
  int mode = (final_mode == 2) ? 2 : ((z == 2) ? 1 : 0);

  f32x4 acc[4][4];
#pragma unroll
  for (int i = 0; i < 4; i++)
#pragma unroll
    for (int j = 0; j < 4; j++) acc[i][j] = (f32x4){0.f, 0.f, 0.f, 0.f};

  for (int kk = 0; kk < 16; kk++) {
    int k0 = kk * 32;
    // stage A (128 rows x 32 k, cvt f32->bf16 if needed) and B tiles
#pragma unroll
    for (int i = 0; i < 2; i++) {
      int flat = tid + i * 256;          // 0..511 segments of 8 elems
      int row = flat >> 2, seg = flat & 3;
      bf16x8 av = load8(A + (size_t)(bm * 128 + row) * DMODEL + k0 + seg * 8);
      *(bf16x8*)(A_s + row * 40 + seg * 8) = av;
      bf16x8 bv = *(const bf16x8*)(WT + (size_t)(bn * 128 + row) * DMODEL + k0 + seg * 8);
      *(bf16x8*)(B_s + row * 40 + seg * 8) = bv;
    }
    __syncthreads();

    bf16x8 a[4], b[4];
#pragma unroll
    for (int i = 0; i < 4; i++)
      a[i] = *(const bf16x8*)(A_s + (wm * 64 + i * 16 + l16) * 40 + quad * 8);
#pragma unroll
    for (int j = 0; j < 4; j++)
      b[j] = *(const bf16x8*)(B_s + (wn * 64 + j * 16 + l16) * 40 + quad * 8);
#pragma unroll
    for (int i = 0; i < 4; i++)
#pragma unroll
      for (int j = 0; j < 4; j++)
        acc[i][j] = __builtin_amdgcn_mfma_f32_16x16x32_bf16(a[i], b[j], acc[i][j], 0, 0, 0);
    __syncthreads();
  }

  // epilogue
#pragma unroll
  for (int j = 0; j < 4; j++) {
    int gc = bn * 128 + wn * 64 + j * 16 + l16;
    float bs = bias[gc];
#pragma unroll
    for (int i = 0; i < 4; i++) {
#pragma unroll
      for (int r = 0; r < 4; r++) {
        int gm = bm * 128 + wm * 64 + i * 16 + quad * 4 + r;
        float val = acc[i][j][r] + bs;
        if (mode == 2) {
          outf[(size_t)gm * DMODEL + gc] = val;
        } else {
          int b = gm >> 8, n = gm & 255, h = gc >> 6, d = gc & 63;
          size_t idx = (mode == 0)
              ? ((size_t)(b * NH + h) * NSEQ + n) * DHEAD + d
              : ((size_t)(b * NH + h) * DHEAD + d) * NSEQ + n;
          outb[(size_t)z * HEAD_T_ELEMS + idx] = (bf16_t)val;
        }
      }
    }
  }
}

// ---------------------------------------------------------------------------
// Attention: block = (qt, h, b), 4 waves x 16 q-rows.
// K tile (256x64) staged in padded LDS [256][72]; after phase A the same
// buffer is reused as P [64][264]. V/pos/mask read direct (L1/L2-served).
__global__ __launch_bounds__(256) void attn_kernel(
    const bf16_t* __restrict__ qh, const bf16_t* __restrict__ kh,
    const bf16_t* __restrict__ vT, const float* __restrict__ pos,
    const int* __restrict__ mask, bf16_t* __restrict__ attw) {
  __shared__ bf16_t KP_s[256 * 72];   // 36,864 B; P (64x264=16,896) aliases it

  int tid = threadIdx.x;
  int wave = tid >> 6, lane = tid & 63, quad = lane >> 4, l16 = lane & 15;
  int qt = blockIdx.x, h = blockIdx.y, b = blockIdx.z;

  const bf16_t* qb = qh + (size_t)(b * NH + h) * NSEQ * DHEAD;
  const bf16_t* kb = kh + (size_t)(b * NH + h) * NSEQ * DHEAD;
  const bf16_t* vb = vT + (size_t)(b * NH + h) * DHEAD * NSEQ;
  // heads share identical pos values; read the h=0 copy for L2 locality
  const float* pb = pos + (size_t)b * NH * NSEQ * NSEQ;
  const int* mrow = mask + b * NSEQ;

  // stage K tile: 256 rows x 64 d -> KP_s rows padded to 72
#pragma unroll
  for (int i = 0; i < 8; i++) {
    int flat = tid + i * 256;            // 2048 segments of 8 elems
    int row = flat >> 3, seg = flat & 7;
    *(bf16x8*)(KP_s + row * 72 + seg * 8) =
        *(const bf16x8*)(kb + (size_t)row * DHEAD + seg * 8);
  }
  __syncthreads();

  int m0 = qt * 64 + wave * 16;

  // Phase A: S = qh @ kh^T (16 key-tiles, K=64 as two 32-chunks) from LDS
  bf16x8 a0 = *(const bf16x8*)(qb + (size_t)(m0 + l16) * DHEAD + quad * 8);
  bf16x8 a1 = *(const bf16x8*)(qb + (size_t)(m0 + l16) * DHEAD + 32 + quad * 8);
  f32x4 s[16];
#pragma unroll
  for (int t = 0; t < 16; t++) s[t] = (f32x4){0.f, 0.f, 0.f, 0.f};
#pragma unroll
  for (int t = 0; t < 16; t++) {
    const bf16_t* krow = KP_s + (t * 16 + l16) * 72;
    bf16x8 b0 = *(const bf16x8*)(krow + quad * 8);
    bf16x8 b1 = *(const bf16x8*)(krow + 32 + quad * 8);
    s[t] = __builtin_amdgcn_mfma_f32_16x16x32_bf16(a0, b0, s[t], 0, 0, 0);
    s[t] = __builtin_amdgcn_mfma_f32_16x16x32_bf16(a1, b1, s[t], 0, 0, 0);
  }

  // Phase B: scale + pos + mask (C-layout: row=quad*4+r, col=t*16+l16)
#pragma unroll
  for (int t = 0; t < 16; t++) {
    int gj = t * 16 + l16;
    int mk = mrow[gj];
#pragma unroll
    for (int r = 0; r < 4; r++) {
      int gr = m0 + quad * 4 + r;
      float v = s[t][r] * 0.125f + pb[(size_t)gr * NSEQ + gj];
      s[t][r] = mk ? -1e9f : v;
    }
  }

  // Register softmax: each row lives across the 16 lanes of a quad.
  float inv[4];
#pragma unroll
  for (int r = 0; r < 4; r++) {
    float m = -1e30f;
#pragma unroll
    for (int t = 0; t < 16; t++) m = fmaxf(m, s[t][r]);
    m = fmaxf(m, __shfl_xor(m, 1));
    m = fmaxf(m, __shfl_xor(m, 2));
    m = fmaxf(m, __shfl_xor(m, 4));
    m = fmaxf(m, __shfl_xor(m, 8));
    float sum = 0.f;
#pragma unroll
    for (int t = 0; t < 16; t++) {
      float e = __expf(s[t][r] - m);
      s[t][r] = e;
      sum += e;
    }
    sum += __shfl_xor(sum, 1);
    sum += __shfl_xor(sum, 2);
    sum += __shfl_xor(sum, 4);
    sum += __shfl_xor(sum, 8);
    inv[r] = 1.0f / sum;
  }

  __syncthreads();   // all phase-A K_s reads complete before P overwrites

  // P (bf16) -> KP_s as [64][264] row-major (A-operand readable)
#pragma unroll
  for (int t = 0; t < 16; t++) {
    int gj = t * 16 + l16;
#pragma unroll
    for (int r = 0; r < 4; r++)
      KP_s[(wave * 16 + quad * 4 + r) * 264 + gj] = (bf16_t)(s[t][r] * inv[r]);
  }
  // no barrier: each wave reads back only its own 16 P rows

  // Phase C: O = P @ V (V pre-transposed [DH][N], direct global B-frags)
  f32x4 o[4];
#pragma unroll
  for (int t2 = 0; t2 < 4; t2++) o[t2] = (f32x4){0.f, 0.f, 0.f, 0.f};
#pragma unroll
  for (int kk = 0; kk < 8; kk++) {
    bf16x8 pa = *(const bf16x8*)(KP_s + (wave * 16 + l16) * 264 + kk * 32 + quad * 8);
#pragma unroll
    for (int t2 = 0; t2 < 4; t2++) {
      bf16x8 vv = *(const bf16x8*)(vb + (size_t)(t2 * 16 + l16) * NSEQ + kk * 32 + quad * 8);
      o[t2] = __builtin_amdgcn_mfma_f32_16x16x32_bf16(pa, vv, o[t2], 0, 0, 0);
    }
  }

  // Epilogue: attw[(b*256+q)*512 + h*64+d]
#pragma unroll
  for (int t2 = 0; t2 < 4; t2++) {
    int d = t2 * 16 + l16;
#pragma unroll
    for (int r = 0; r < 4; r++) {
      int gr = m0 + quad * 4 + r;
      attw[(size_t)(b * NSEQ + gr) * DMODEL + h * DHEAD + d] = (bf16_t)o[t2][r];
    }
  }
}

// ---------------------------------------------------------------------------
extern "C" void kernel_launch(void* const* d_in, const int* in_sizes, int n_in,
                              void* d_out, int out_size, void* d_ws, size_t ws_size,
                              hipStream_t stream) {
  const float* v    = (const float*)d_in[0];
  const float* k    = (const float*)d_in[1];
  const float* q    = (const float*)d_in[2];
  const float* box  = (const float*)d_in[3];
  const int*   mask = (const int*)d_in[4];
  // d_in[5] = fg (always 2; branch fixed)
  const float* Wq   = (const float*)d_in[6];
  const float* bq   = (const float*)d_in[7];
  const float* Wk   = (const float*)d_in[8];
  const float* bk   = (const float*)d_in[9];
  const float* Wv   = (const float*)d_in[10];
  const float* bv   = (const float*)d_in[11];
  const float* Wm   = (const float*)d_in[12];
  const float* bm   = (const float*)d_in[13];
  const float* Wbox = (const float*)d_in[14];
  const float* bbox = (const float*)d_in[15];

  float* out  = (float*)d_out;
  bf16_t* ws  = (bf16_t*)d_ws;
  bf16_t* WT   = ws + WS_WT;
  bf16_t* qh   = ws + WS_QH;                      // q: +0, k: +4.19M, vT: +8.39M
  bf16_t* khw  = qh + 1 * HEAD_T_ELEMS;
  bf16_t* vTp  = qh + 2 * HEAD_T_ELEMS;
  bf16_t* attw = ws + WS_ATTW;
  float* pos  = out + ATTED_ELEMS;                // pos_scores region (f32)

  transpose_kernel<<<dim3(8, 8, 4), dim3(256), 0, stream>>>(Wq, Wk, Wv, Wm, WT);
  pos_kernel<<<dim3(NB * NSEQ), dim3(256), 0, stream>>>(box, Wbox, bbox, pos);
  gemm128_kernel<float><<<dim3(64, 4, 3), dim3(256), 0, stream>>>(
      q, k, v, WT, bq, bk, bv, qh, out, 0);
  attn_kernel<<<dim3(NSEQ / 64, NH, NB), dim3(256), 0, stream>>>(
      qh, khw, vTp, pos, mask, attw);
  gemm128_kernel<bf16_t><<<dim3(64, 4, 1), dim3(256), 0, stream>>>(
      attw, attw, attw, WT, bm, bm, bm, qh, out, 2);
}